// Round 1
// baseline (5260.844 us; speedup 1.0000x reference)
//
#include <hip/hip_runtime.h>
#include <hip/hip_bf16.h>
#include <cstddef>

#define NN 200000   // nodes
#define NE 400000   // edges
#define DD 128      // embed dim
#define NL 5        // layers
#define NG 1000     // graphs
#define BOND_V 5
#define BM 32       // gemm rows per block
#define NBLK (NN / BM)   // 6250
#define CHUNK 200        // pool chunk (NN / CHUNK = 1000 blocks)
#define EPS 1e-5f

// ---------------- degree / counts ----------------
__global__ void k_deg(const int* __restrict__ dst, float* __restrict__ deg) {
    int e = blockIdx.x * blockDim.x + threadIdx.x;
    if (e < NE) atomicAdd(&deg[dst[e]], 1.0f);
}

__global__ void k_cnt(const int* __restrict__ n2g, float* __restrict__ gcnt) {
    int n = blockIdx.x * blockDim.x + threadIdx.x;
    if (n < NN) atomicAdd(&gcnt[n2g[n]], 1.0f);
}

__global__ void k_rdeg(float* __restrict__ deg) {
    int n = blockIdx.x * blockDim.x + threadIdx.x;
    if (n < NN) deg[n] = 1.0f / (deg[n] + 1.0f);
}

// ---------------- h0 = atom_emb[nfeat] ----------------
__global__ void k_gather(const int* __restrict__ nfeat,
                         const float* __restrict__ aemb,
                         float* __restrict__ A) {
    int idx = blockIdx.x * blockDim.x + threadIdx.x;   // NN*32 threads
    int n = idx >> 5, c4 = (idx & 31) << 2;
    float4 v = *(const float4*)(aemb + (size_t)nfeat[n] * DD + c4);
    *(float4*)(A + (size_t)n * DD + c4) = v;
}

// ---------------- scatter: B[dst] += h[src] + eemb[efeat] ----------------
__global__ void k_scatter(const int* __restrict__ src, const int* __restrict__ dst,
                          const int* __restrict__ efeat, const float* __restrict__ eemb,
                          const float* __restrict__ A, float* __restrict__ B) {
    int idx = blockIdx.x * blockDim.x + threadIdx.x;   // NE*32 threads
    int e = idx >> 5, c4 = (idx & 31) << 2;
    int s = src[e], t = dst[e], f = efeat[e];
    float4 hv = *(const float4*)(A + (size_t)s * DD + c4);
    float4 ev = *(const float4*)(eemb + (size_t)f * DD + c4);
    float* p = B + (size_t)t * DD + c4;
    atomicAdd(p + 0, hv.x + ev.x);
    atomicAdd(p + 1, hv.y + ev.y);
    atomicAdd(p + 2, hv.z + ev.z);
    atomicAdd(p + 3, hv.w + ev.w);
}

// ---------------- GEMM: C = ((A+B)*rdeg) @ W + bias, in place on A ----------------
// + fused BN-stat partials (column sum / sumsq) -> part[2][128][NBLK]
#define XP 132   // padded X row stride (breaks bank conflicts)
__global__ __launch_bounds__(256, 2)
void k_gemm(const float* A_in, const float* __restrict__ B,
            const float* __restrict__ rdeg, const float* __restrict__ W,
            const float* __restrict__ bias, float* C,
            float* __restrict__ part) {
    __shared__ float Ws[64 * DD];     // 32 KB, staged in 2 phases of 64 k-rows
    __shared__ float Xs[BM * XP];     // 16.9 KB (also reused as reduce buffer)
    int tid = threadIdx.x;
    int n0 = blockIdx.x * BM;

    // stage X = (A+B)*rdeg : 32x128 floats
    #pragma unroll
    for (int i = 0; i < 4; i++) {
        int idx = i * 256 + tid;           // 0..1023 float4 slots
        int r = idx >> 5, k4 = (idx & 31) << 2;
        int n = n0 + r;
        float rd = rdeg[n];
        float4 a = *(const float4*)(A_in + (size_t)n * DD + k4);
        float4 bb = *(const float4*)(B + (size_t)n * DD + k4);
        float* x = Xs + r * XP + k4;
        x[0] = (a.x + bb.x) * rd;
        x[1] = (a.y + bb.y) * rd;
        x[2] = (a.z + bb.z) * rd;
        x[3] = (a.w + bb.w) * rd;
    }

    int tx = tid & 31, ty = tid >> 5;
    int c0 = tx << 2;      // 4 output cols
    int r0 = ty << 2;      // 4 output rows
    float acc[4][4] = {};

    for (int ph = 0; ph < 2; ph++) {
        // stage 64 k-rows of W (8192 floats)
        #pragma unroll
        for (int i = 0; i < 8; i++) {
            int idx = i * 256 + tid;       // float4 slots
            *(float4*)(Ws + idx * 4) = *(const float4*)(W + ph * 64 * DD + idx * 4);
        }
        __syncthreads();
        #pragma unroll
        for (int k = 0; k < 64; k += 4) {
            float4 xq[4], wq[4];
            #pragma unroll
            for (int rr = 0; rr < 4; rr++)
                xq[rr] = *(const float4*)(Xs + (r0 + rr) * XP + ph * 64 + k);
            #pragma unroll
            for (int kk = 0; kk < 4; kk++)
                wq[kk] = *(const float4*)(Ws + (k + kk) * DD + c0);
            #pragma unroll
            for (int rr = 0; rr < 4; rr++) {
                float4 x = xq[rr];
                acc[rr][0] += x.x * wq[0].x + x.y * wq[1].x + x.z * wq[2].x + x.w * wq[3].x;
                acc[rr][1] += x.x * wq[0].y + x.y * wq[1].y + x.z * wq[2].y + x.w * wq[3].y;
                acc[rr][2] += x.x * wq[0].z + x.y * wq[1].z + x.z * wq[2].z + x.w * wq[3].z;
                acc[rr][3] += x.x * wq[0].w + x.y * wq[1].w + x.z * wq[2].w + x.w * wq[3].w;
            }
        }
        __syncthreads();
    }

    // bias + store (in place on A: this block staged its rows already; barrier-ordered)
    float4 bv = *(const float4*)(bias + c0);
    #pragma unroll
    for (int rr = 0; rr < 4; rr++) {
        acc[rr][0] += bv.x; acc[rr][1] += bv.y; acc[rr][2] += bv.z; acc[rr][3] += bv.w;
        float4 o; o.x = acc[rr][0]; o.y = acc[rr][1]; o.z = acc[rr][2]; o.w = acc[rr][3];
        *(float4*)(C + (size_t)(n0 + r0 + rr) * DD + c0) = o;
    }

    // column partials over this thread's 4 rows
    float s[4], q[4];
    #pragma unroll
    for (int cc = 0; cc < 4; cc++) {
        s[cc] = acc[0][cc] + acc[1][cc] + acc[2][cc] + acc[3][cc];
        q[cc] = acc[0][cc]*acc[0][cc] + acc[1][cc]*acc[1][cc]
              + acc[2][cc]*acc[2][cc] + acc[3][cc]*acc[3][cc];
    }
    // reuse Xs as reduce buffer: [8][128] sums + [8][128] sumsq = 2048 floats
    float* red = Xs;
    #pragma unroll
    for (int cc = 0; cc < 4; cc++) {
        red[ty * DD + c0 + cc] = s[cc];
        red[1024 + ty * DD + c0 + cc] = q[cc];
    }
    __syncthreads();
    if (tid < DD) {
        float ss = 0.f, qq = 0.f;
        #pragma unroll
        for (int t = 0; t < 8; t++) {
            ss += red[t * DD + tid];
            qq += red[1024 + t * DD + tid];
        }
        part[(size_t)tid * NBLK + blockIdx.x] = ss;
        part[(size_t)(DD + tid) * NBLK + blockIdx.x] = qq;
    }
}

// ---------------- reduce BN stats: mu, rsigma per column ----------------
__global__ void k_stats(const float* __restrict__ part,
                        float* __restrict__ mu, float* __restrict__ rs) {
    int col = blockIdx.x;
    float s = 0.f, q = 0.f;
    for (int i = threadIdx.x; i < NBLK; i += 256) {
        s += part[(size_t)col * NBLK + i];
        q += part[(size_t)(DD + col) * NBLK + i];
    }
    #pragma unroll
    for (int o = 32; o > 0; o >>= 1) {
        s += __shfl_down(s, o);
        q += __shfl_down(q, o);
    }
    __shared__ float sh[8];
    int lane = threadIdx.x & 63, w = threadIdx.x >> 6;
    if (lane == 0) { sh[w] = s; sh[4 + w] = q; }
    __syncthreads();
    if (threadIdx.x == 0) {
        float S = sh[0] + sh[1] + sh[2] + sh[3];
        float Q = sh[4] + sh[5] + sh[6] + sh[7];
        float m = S / (float)NN;
        float v = Q / (float)NN - m * m;
        mu[col] = m;
        rs[col] = rsqrtf(v + EPS);
    }
}

// ---------------- BN + ReLU, in place ----------------
__global__ void k_bnrelu(float* __restrict__ A, const float* __restrict__ mu,
                         const float* __restrict__ rs, const float* __restrict__ gamma,
                         const float* __restrict__ beta) {
    int idx = blockIdx.x * blockDim.x + threadIdx.x;   // NN*32
    int n = idx >> 5, c4 = (idx & 31) << 2;
    float4 x = *(float4*)(A + (size_t)n * DD + c4);
    float4 m = *(const float4*)(mu + c4);
    float4 r = *(const float4*)(rs + c4);
    float4 g = *(const float4*)(gamma + c4);
    float4 bt = *(const float4*)(beta + c4);
    x.x = fmaxf(0.f, (x.x - m.x) * r.x * g.x + bt.x);
    x.y = fmaxf(0.f, (x.y - m.y) * r.y * g.y + bt.y);
    x.z = fmaxf(0.f, (x.z - m.z) * r.z * g.z + bt.z);
    x.w = fmaxf(0.f, (x.w - m.w) * r.w * g.w + bt.w);
    *(float4*)(A + (size_t)n * DD + c4) = x;
}

// ---------------- last layer: BN + ReLU fused with graph-sum pooling ----------------
// exploits sorted node2graph: per-block local accumulation, flush on graph change
__global__ void k_bnpool(const float* __restrict__ A, const int* __restrict__ n2g,
                         const float* __restrict__ mu, const float* __restrict__ rs,
                         const float* __restrict__ gamma, const float* __restrict__ beta,
                         float* __restrict__ gsum) {
    int j = threadIdx.x;              // 0..127 = feature
    int n0 = blockIdx.x * CHUNK;
    float m = mu[j], r = rs[j], ga = gamma[j], be = beta[j];
    int cur = n2g[n0];
    float acc = 0.f;
    for (int i = 0; i < CHUNK; i++) {
        int n = n0 + i;
        int gg = n2g[n];
        if (gg != cur) {
            atomicAdd(&gsum[(size_t)cur * DD + j], acc);
            acc = 0.f;
            cur = gg;
        }
        float x = A[(size_t)n * DD + j];
        x = fmaxf(0.f, (x - m) * r * ga + be);
        acc += x;
    }
    atomicAdd(&gsum[(size_t)cur * DD + j], acc);
}

// ---------------- final MLP: out = relu(g@W1+b1)@W2+b2 ----------------
__global__ void k_mlp(const float* __restrict__ gsum, const float* __restrict__ gcnt,
                      const float* __restrict__ W1, const float* __restrict__ b1,
                      const float* __restrict__ W2, const float* __restrict__ b2,
                      float* __restrict__ out) {
    __shared__ float gs[DD], hs[DD];
    int gid = blockIdx.x, j = threadIdx.x;
    float inv = 1.0f / fmaxf(gcnt[gid], 1.0f);
    gs[j] = gsum[(size_t)gid * DD + j] * inv;
    __syncthreads();
    float a = b1[j];
    for (int k = 0; k < DD; k++) a += gs[k] * W1[k * DD + j];
    hs[j] = fmaxf(a, 0.f);
    __syncthreads();
    float o = b2[j];
    for (int k = 0; k < DD; k++) o += hs[k] * W2[k * DD + j];
    out[(size_t)gid * DD + j] = o;
}

extern "C" void kernel_launch(void* const* d_in, const int* in_sizes, int n_in,
                              void* d_out, int out_size, void* d_ws, size_t ws_size,
                              hipStream_t stream) {
    const int*   nfeat = (const int*)d_in[0];
    const int*   efeat = (const int*)d_in[1];
    const int*   src   = (const int*)d_in[2];
    const int*   dst   = (const int*)d_in[3];
    const int*   n2g   = (const int*)d_in[4];
    const float* aemb  = (const float*)d_in[5];
    const float* eemb  = (const float*)d_in[6];   // [L][5][128]
    const float* Wl    = (const float*)d_in[7];   // [L][128][128]
    const float* bl    = (const float*)d_in[8];   // [L][128]
    const float* gam   = (const float*)d_in[9];
    const float* bet   = (const float*)d_in[10];
    const float* W1    = (const float*)d_in[11];
    const float* b1    = (const float*)d_in[12];
    const float* W2    = (const float*)d_in[13];
    const float* b2    = (const float*)d_in[14];
    float* out = (float*)d_out;

    float* ws   = (float*)d_ws;
    float* A    = ws;                          // NN*DD
    float* B    = A + (size_t)NN * DD;         // NN*DD
    float* rdeg = B + (size_t)NN * DD;         // NN
    float* gsum = rdeg + NN;                   // NG*DD
    float* gcnt = gsum + (size_t)NG * DD;      // NG
    float* mu   = gcnt + NG;                   // DD
    float* rs   = mu + DD;                     // DD
    float* part = rs + DD;                     // 2*DD*NBLK

    // zero: rdeg + gsum + gcnt (contiguous)
    hipMemsetAsync(rdeg, 0, (size_t)(NN + NG * DD + NG) * sizeof(float), stream);
    k_deg<<<(NE + 255) / 256, 256, 0, stream>>>(dst, rdeg);
    k_cnt<<<(NN + 255) / 256, 256, 0, stream>>>(n2g, gcnt);
    k_rdeg<<<(NN + 255) / 256, 256, 0, stream>>>(rdeg);
    k_gather<<<NN * 32 / 256, 256, 0, stream>>>(nfeat, aemb, A);

    for (int l = 0; l < NL; l++) {
        hipMemsetAsync(B, 0, (size_t)NN * DD * sizeof(float), stream);
        k_scatter<<<NE * 32 / 256, 256, 0, stream>>>(src, dst, efeat,
                                                     eemb + (size_t)l * BOND_V * DD, A, B);
        k_gemm<<<NBLK, 256, 0, stream>>>(A, B, rdeg, Wl + (size_t)l * DD * DD,
                                         bl + (size_t)l * DD, A, part);
        k_stats<<<DD, 256, 0, stream>>>(part, mu, rs);
        if (l < NL - 1)
            k_bnrelu<<<NN * 32 / 256, 256, 0, stream>>>(A, mu, rs,
                                                        gam + (size_t)l * DD, bet + (size_t)l * DD);
        else
            k_bnpool<<<NN / CHUNK, DD, 0, stream>>>(A, n2g, mu, rs,
                                                    gam + (size_t)l * DD, bet + (size_t)l * DD, gsum);
    }
    k_mlp<<<NG, DD, 0, stream>>>(gsum, gcnt, W1, b1, W2, b2, out);
}

// Round 2
// 1510.489 us; speedup vs baseline: 3.4829x; 3.4829x over previous
//
#include <hip/hip_runtime.h>
#include <hip/hip_bf16.h>
#include <cstddef>

#define NN 200000   // nodes
#define NE 400000   // edges
#define DD 128      // embed dim
#define NL 5        // layers
#define NG 1000     // graphs
#define BOND_V 5
#define BM2 64            // gemm rows per block
#define NBLK2 (NN / BM2)  // 3125
#define CHUNK 200         // pool chunk (NN/CHUNK = 1000 blocks)
#define NB_SCAN 200       // scan blocks
#define CH 1000           // scan chunk (NB_SCAN*CH == NN)
#define EPS 1e-5f

// ---------------- degree (int) / graph counts ----------------
__global__ void k_deg_int(const int* __restrict__ dst, int* __restrict__ cnt) {
    int e = blockIdx.x * blockDim.x + threadIdx.x;
    if (e < NE) atomicAdd(&cnt[dst[e]], 1);
}

__global__ void k_cnt(const int* __restrict__ n2g, float* __restrict__ gcnt) {
    int n = blockIdx.x * blockDim.x + threadIdx.x;
    if (n < NN) atomicAdd(&gcnt[n2g[n]], 1.0f);
}

__global__ void k_rdeg(const int* __restrict__ cnt, float* __restrict__ rdeg) {
    int n = blockIdx.x * blockDim.x + threadIdx.x;
    if (n < NN) rdeg[n] = 1.0f / (float)(cnt[n] + 1);
}

// ---------------- CSR build: 2-level exclusive scan + bucket fill ----------------
__global__ void k_scan1(const int* __restrict__ cnt, int* __restrict__ bsum) {
    __shared__ int sh[256];
    int b = blockIdx.x, t = threadIdx.x;
    int s = 0;
    if (t < CH / 4) {
        int base = b * CH + t * 4;
        s = cnt[base] + cnt[base + 1] + cnt[base + 2] + cnt[base + 3];
    }
    sh[t] = s;
    __syncthreads();
    if (t == 0) {
        int tot = 0;
        for (int i = 0; i < CH / 4; i++) tot += sh[i];
        bsum[b] = tot;
    }
}

__global__ void k_scan2(const int* __restrict__ bsum, int* __restrict__ bpre,
                        int* __restrict__ off) {
    if (threadIdx.x == 0) {
        int run = 0;
        for (int i = 0; i < NB_SCAN; i++) { bpre[i] = run; run += bsum[i]; }
        off[NN] = NE;
    }
}

__global__ void k_scan3(const int* __restrict__ cnt, const int* __restrict__ bpre,
                        int* __restrict__ off, int* __restrict__ cur) {
    __shared__ int sh[256];
    int b = blockIdx.x, t = threadIdx.x;
    int base = b * CH + t * 4;
    int c0 = 0, c1 = 0, c2 = 0, c3 = 0, s = 0;
    if (t < CH / 4) {
        c0 = cnt[base]; c1 = cnt[base + 1]; c2 = cnt[base + 2]; c3 = cnt[base + 3];
        s = c0 + c1 + c2 + c3;
    }
    sh[t] = s;
    __syncthreads();
    if (t == 0) {
        int run = bpre[b];
        for (int i = 0; i < CH / 4; i++) { int v = sh[i]; sh[i] = run; run += v; }
    }
    __syncthreads();
    if (t < CH / 4) {
        int run = sh[t];
        off[base] = run; cur[base] = run; run += c0;
        off[base + 1] = run; cur[base + 1] = run; run += c1;
        off[base + 2] = run; cur[base + 2] = run; run += c2;
        off[base + 3] = run; cur[base + 3] = run;
    }
}

__global__ void k_bucket(const int* __restrict__ src, const int* __restrict__ dst,
                         const int* __restrict__ efeat, int* __restrict__ cur,
                         int* __restrict__ esrc, int* __restrict__ eft) {
    int e = blockIdx.x * blockDim.x + threadIdx.x;
    if (e < NE) {
        int p = atomicAdd(&cur[dst[e]], 1);
        esrc[p] = src[e];
        eft[p] = efeat[e];
    }
}

// ---------------- fused BN+ReLU helper ----------------
__device__ __forceinline__ float4 bnrelu4(float4 x, float4 m, float4 r, float4 g, float4 b) {
    float4 o;
    o.x = fmaxf(0.f, (x.x - m.x) * r.x * g.x + b.x);
    o.y = fmaxf(0.f, (x.y - m.y) * r.y * g.y + b.y);
    o.z = fmaxf(0.f, (x.z - m.z) * r.z * g.z + b.z);
    o.w = fmaxf(0.f, (x.w - m.w) * r.w * g.w + b.w);
    return o;
}

// ---------------- aggregation (CSR gather), fuses BN+ReLU of prev layer,
// degree norm and self-term: X[n] = (h[n] + sum_in (h[src]+e[feat])) * rdeg[n]
// first=1: base = atom_emb, rows indirected via nfeat, no BN.
__global__ __launch_bounds__(256)
void k_agg(const float* __restrict__ base, const int* __restrict__ nfeat, int first,
           const int* __restrict__ off, const int* __restrict__ esrc,
           const int* __restrict__ eft, const float* __restrict__ eemb,
           const float* __restrict__ rdeg,
           const float* __restrict__ mu, const float* __restrict__ rsig,
           const float* __restrict__ gamma, const float* __restrict__ beta,
           float* __restrict__ X) {
    __shared__ float eS[BOND_V * DD];
    int tid = threadIdx.x;
    if (tid < BOND_V * DD / 4)
        *(float4*)(eS + tid * 4) = *(const float4*)(eemb + tid * 4);
    int lane = tid & 31, grp = tid >> 5;
    int n = blockIdx.x * 8 + grp;
    int c4 = lane << 2;
    float4 m4, r4, g4, b4;
    if (!first) {
        m4 = *(const float4*)(mu + c4);
        r4 = *(const float4*)(rsig + c4);
        g4 = *(const float4*)(gamma + c4);
        b4 = *(const float4*)(beta + c4);
    }
    __syncthreads();
    int e0 = off[n], e1 = off[n + 1];
    int rown = first ? nfeat[n] : n;
    float4 acc = *(const float4*)(base + (size_t)rown * DD + c4);
    if (!first) acc = bnrelu4(acc, m4, r4, g4, b4);
    for (int k = e0; k < e1; k++) {
        int s = esrc[k];
        int rowe = first ? nfeat[s] : s;
        float4 hv = *(const float4*)(base + (size_t)rowe * DD + c4);
        if (!first) hv = bnrelu4(hv, m4, r4, g4, b4);
        float4 ev = *(const float4*)(eS + eft[k] * DD + c4);
        acc.x += hv.x + ev.x;
        acc.y += hv.y + ev.y;
        acc.z += hv.z + ev.z;
        acc.w += hv.w + ev.w;
    }
    float rd = rdeg[n];
    acc.x *= rd; acc.y *= rd; acc.z *= rd; acc.w *= rd;
    *(float4*)(X + (size_t)n * DD + c4) = acc;
}

// ---------------- GEMM: C = X @ W + bias, fused BN-stat partials ----------------
__global__ __launch_bounds__(256, 4)
void k_gemm(const float* __restrict__ X, const float* __restrict__ W,
            const float* __restrict__ bias, float* __restrict__ C,
            float* __restrict__ part) {
    __shared__ float Ws[32 * DD];     // 16 KB, staged in 4 phases
    __shared__ float Xs[BM2 * DD];    // 32 KB (reads are broadcast -> no pad needed)
    int tid = threadIdx.x;
    int n0 = blockIdx.x * BM2;

    #pragma unroll
    for (int i = 0; i < 8; i++) {
        int idx = i * 256 + tid;      // 2048 float4 slots
        *(float4*)(Xs + idx * 4) = *(const float4*)(X + (size_t)n0 * DD + idx * 4);
    }

    int tx = tid & 31, ty = tid >> 5;
    int c0 = tx << 2;     // 4 output cols
    int r0 = ty << 3;     // 8 output rows
    float acc[8][4] = {};

    for (int ph = 0; ph < 4; ph++) {
        #pragma unroll
        for (int i = 0; i < 4; i++) {
            int idx = i * 256 + tid;  // 1024 float4 slots
            *(float4*)(Ws + idx * 4) = *(const float4*)(W + ph * 32 * DD + idx * 4);
        }
        __syncthreads();
        #pragma unroll
        for (int k = 0; k < 32; k += 4) {
            float4 wq[4];
            #pragma unroll
            for (int kk = 0; kk < 4; kk++)
                wq[kk] = *(const float4*)(Ws + (k + kk) * DD + c0);
            #pragma unroll
            for (int rr = 0; rr < 8; rr++) {
                float4 x = *(const float4*)(Xs + (r0 + rr) * DD + ph * 32 + k);
                acc[rr][0] += x.x * wq[0].x + x.y * wq[1].x + x.z * wq[2].x + x.w * wq[3].x;
                acc[rr][1] += x.x * wq[0].y + x.y * wq[1].y + x.z * wq[2].y + x.w * wq[3].y;
                acc[rr][2] += x.x * wq[0].z + x.y * wq[1].z + x.z * wq[2].z + x.w * wq[3].z;
                acc[rr][3] += x.x * wq[0].w + x.y * wq[1].w + x.z * wq[2].w + x.w * wq[3].w;
            }
        }
        __syncthreads();
    }

    float4 bv = *(const float4*)(bias + c0);
    #pragma unroll
    for (int rr = 0; rr < 8; rr++) {
        acc[rr][0] += bv.x; acc[rr][1] += bv.y; acc[rr][2] += bv.z; acc[rr][3] += bv.w;
        float4 o; o.x = acc[rr][0]; o.y = acc[rr][1]; o.z = acc[rr][2]; o.w = acc[rr][3];
        *(float4*)(C + (size_t)(n0 + r0 + rr) * DD + c0) = o;
    }

    // column partials over this thread's 8 rows -> part[2][128][NBLK2]
    float s[4], q[4];
    #pragma unroll
    for (int cc = 0; cc < 4; cc++) {
        s[cc] = 0.f; q[cc] = 0.f;
        #pragma unroll
        for (int rr = 0; rr < 8; rr++) {
            s[cc] += acc[rr][cc];
            q[cc] += acc[rr][cc] * acc[rr][cc];
        }
    }
    float* red = Xs;   // reuse (2048 floats)
    #pragma unroll
    for (int cc = 0; cc < 4; cc++) {
        red[ty * DD + c0 + cc] = s[cc];
        red[1024 + ty * DD + c0 + cc] = q[cc];
    }
    __syncthreads();
    if (tid < DD) {
        float ss = 0.f, qq = 0.f;
        #pragma unroll
        for (int t = 0; t < 8; t++) {
            ss += red[t * DD + tid];
            qq += red[1024 + t * DD + tid];
        }
        part[(size_t)tid * NBLK2 + blockIdx.x] = ss;
        part[(size_t)(DD + tid) * NBLK2 + blockIdx.x] = qq;
    }
}

// ---------------- reduce BN stats ----------------
__global__ void k_stats(const float* __restrict__ part,
                        float* __restrict__ mu, float* __restrict__ rsig) {
    int col = blockIdx.x;
    float s = 0.f, q = 0.f;
    for (int i = threadIdx.x; i < NBLK2; i += 256) {
        s += part[(size_t)col * NBLK2 + i];
        q += part[(size_t)(DD + col) * NBLK2 + i];
    }
    #pragma unroll
    for (int o = 32; o > 0; o >>= 1) {
        s += __shfl_down(s, o);
        q += __shfl_down(q, o);
    }
    __shared__ float sh[8];
    int lane = threadIdx.x & 63, w = threadIdx.x >> 6;
    if (lane == 0) { sh[w] = s; sh[4 + w] = q; }
    __syncthreads();
    if (threadIdx.x == 0) {
        float S = sh[0] + sh[1] + sh[2] + sh[3];
        float Q = sh[4] + sh[5] + sh[6] + sh[7];
        float m = S / (float)NN;
        float v = Q / (float)NN - m * m;
        mu[col] = m;
        rsig[col] = rsqrtf(v + EPS);
    }
}

// ---------------- last layer: BN + ReLU fused with graph-sum pooling ----------------
__global__ void k_bnpool(const float* __restrict__ A, const int* __restrict__ n2g,
                         const float* __restrict__ mu, const float* __restrict__ rsig,
                         const float* __restrict__ gamma, const float* __restrict__ beta,
                         float* __restrict__ gsum) {
    int j = threadIdx.x;
    int n0 = blockIdx.x * CHUNK;
    float m = mu[j], r = rsig[j], ga = gamma[j], be = beta[j];
    int cur = n2g[n0];
    float acc = 0.f;
    for (int i = 0; i < CHUNK; i++) {
        int n = n0 + i;
        int gg = n2g[n];
        if (gg != cur) {
            atomicAdd(&gsum[(size_t)cur * DD + j], acc);
            acc = 0.f;
            cur = gg;
        }
        float x = A[(size_t)n * DD + j];
        x = fmaxf(0.f, (x - m) * r * ga + be);
        acc += x;
    }
    atomicAdd(&gsum[(size_t)cur * DD + j], acc);
}

// ---------------- final MLP ----------------
__global__ void k_mlp(const float* __restrict__ gsum, const float* __restrict__ gcnt,
                      const float* __restrict__ W1, const float* __restrict__ b1,
                      const float* __restrict__ W2, const float* __restrict__ b2,
                      float* __restrict__ out) {
    __shared__ float gs[DD], hs[DD];
    int gid = blockIdx.x, j = threadIdx.x;
    float inv = 1.0f / fmaxf(gcnt[gid], 1.0f);
    gs[j] = gsum[(size_t)gid * DD + j] * inv;
    __syncthreads();
    float a = b1[j];
    for (int k = 0; k < DD; k++) a += gs[k] * W1[k * DD + j];
    hs[j] = fmaxf(a, 0.f);
    __syncthreads();
    float o = b2[j];
    for (int k = 0; k < DD; k++) o += hs[k] * W2[k * DD + j];
    out[(size_t)gid * DD + j] = o;
}

extern "C" void kernel_launch(void* const* d_in, const int* in_sizes, int n_in,
                              void* d_out, int out_size, void* d_ws, size_t ws_size,
                              hipStream_t stream) {
    const int*   nfeat = (const int*)d_in[0];
    const int*   efeat = (const int*)d_in[1];
    const int*   src   = (const int*)d_in[2];
    const int*   dst   = (const int*)d_in[3];
    const int*   n2g   = (const int*)d_in[4];
    const float* aemb  = (const float*)d_in[5];
    const float* eemb  = (const float*)d_in[6];   // [L][5][128]
    const float* Wl    = (const float*)d_in[7];   // [L][128][128]
    const float* bl    = (const float*)d_in[8];   // [L][128]
    const float* gam   = (const float*)d_in[9];
    const float* bet   = (const float*)d_in[10];
    const float* W1    = (const float*)d_in[11];
    const float* b1    = (const float*)d_in[12];
    const float* W2    = (const float*)d_in[13];
    const float* b2    = (const float*)d_in[14];
    float* out = (float*)d_out;

    float* ws   = (float*)d_ws;
    float* A    = ws;                          // NN*DD  (GEMM output / h)
    float* X    = A + (size_t)NN * DD;         // NN*DD  (agg output)
    float* rdeg = X + (size_t)NN * DD;         // NN
    float* gsum = rdeg + NN;                   // NG*DD
    float* gcnt = gsum + (size_t)NG * DD;      // NG
    float* mu   = gcnt + NG;                   // DD
    float* rsg  = mu + DD;                     // DD
    float* part = rsg + DD;                    // 2*DD*NBLK2 = 800000 floats
    // cnt/bsum/bpre alias the part region (dead before first gemm)
    int* cnt  = (int*)part;                    // NN
    int* bsum = (int*)part + 300000;           // NB_SCAN
    int* bpre = (int*)part + 301000;           // NB_SCAN
    int* off  = (int*)(part + (size_t)2 * DD * NBLK2);   // NN+1 (persistent)
    int* cur  = off + NN + 1;                  // NN
    int* esrc = cur + NN;                      // NE
    int* eft  = esrc + NE;                     // NE

    hipMemsetAsync(cnt, 0, (size_t)NN * sizeof(int), stream);
    hipMemsetAsync(gsum, 0, (size_t)(NG * DD + NG) * sizeof(float), stream);

    k_deg_int<<<(NE + 255) / 256, 256, 0, stream>>>(dst, cnt);
    k_cnt<<<(NN + 255) / 256, 256, 0, stream>>>(n2g, gcnt);
    k_scan1<<<NB_SCAN, 256, 0, stream>>>(cnt, bsum);
    k_scan2<<<1, 64, 0, stream>>>(bsum, bpre, off);
    k_scan3<<<NB_SCAN, 256, 0, stream>>>(cnt, bpre, off, cur);
    k_rdeg<<<(NN + 255) / 256, 256, 0, stream>>>(cnt, rdeg);
    k_bucket<<<(NE + 255) / 256, 256, 0, stream>>>(src, dst, efeat, cur, esrc, eft);

    for (int l = 0; l < NL; l++) {
        const float* base = (l == 0) ? aemb : A;
        const float* g_prev = (l == 0) ? gam : gam + (size_t)(l - 1) * DD;
        const float* b_prev = (l == 0) ? bet : bet + (size_t)(l - 1) * DD;
        k_agg<<<NN / 8, 256, 0, stream>>>(base, nfeat, (l == 0) ? 1 : 0,
                                          off, esrc, eft,
                                          eemb + (size_t)l * BOND_V * DD, rdeg,
                                          mu, rsg, g_prev, b_prev, X);
        k_gemm<<<NBLK2, 256, 0, stream>>>(X, Wl + (size_t)l * DD * DD,
                                          bl + (size_t)l * DD, A, part);
        k_stats<<<DD, 256, 0, stream>>>(part, mu, rsg);
    }
    k_bnpool<<<NN / CHUNK, DD, 0, stream>>>(A, n2g, mu, rsg,
                                            gam + (size_t)(NL - 1) * DD,
                                            bet + (size_t)(NL - 1) * DD, gsum);
    k_mlp<<<NG, DD, 0, stream>>>(gsum, gcnt, W1, b1, W2, b2, out);
}